// Round 18
// baseline (461.683 us; speedup 1.0000x reference)
//
#include <hip/hip_runtime.h>

typedef __bf16 bf16x8 __attribute__((ext_vector_type(8)));
typedef float f32x4 __attribute__((ext_vector_type(4)));
typedef short short8 __attribute__((ext_vector_type(8)));

__device__ __forceinline__ unsigned short f2bf_u(float f) {
    unsigned u = __builtin_bit_cast(unsigned, f);
    u += 0x7FFFu + ((u >> 16) & 1u);   // RNE
    return (unsigned short)(u >> 16);
}
__device__ __forceinline__ float bf2f(unsigned short h) {
    unsigned u = ((unsigned)h) << 16;
    return __builtin_bit_cast(float, u);
}
__device__ __forceinline__ float i2f(int b) { return __builtin_bit_cast(float, b); }

#define GLOAD_LDS16(gsrc, ldst)                                                        \
    __builtin_amdgcn_global_load_lds((const __attribute__((address_space(1))) void*)(gsrc), \
                                     (__attribute__((address_space(3))) void*)(ldst), 16, 0, 0)

// ==================================================================
// prep_a: flag init+detect (block 0), counts zeroing, weight splits.
// ==================================================================
__global__ __launch_bounds__(256)
void prep_a(const void* __restrict__ ei, const float* __restrict__ W1,
            const float* __restrict__ W2, int* __restrict__ flag,
            short* __restrict__ W1h, short* __restrict__ W1l,
            short* __restrict__ W2h, short* __restrict__ W2l,
            int* __restrict__ counts, int N) {
    __shared__ int sflag;
    const int tid = threadIdx.x;
    const int gtid = blockIdx.x * 256 + tid;
    const int gsize = gridDim.x * 256;
    if (blockIdx.x == 0) {
        if (tid == 0) sflag = 0;
        __syncthreads();
        unsigned v = 0;
        for (int i = tid * 2 + 1; i < 2048; i += 512) v |= ((const unsigned*)ei)[i];
        if (v) atomicOr(&sflag, 1);
        __syncthreads();
        if (tid == 0) *flag = sflag;   // nonzero odd words => int32 input
    }
    for (int i = gtid; i < N; i += gsize) counts[i] = 0;
    const int n1 = 256 * 512, n2 = 64 * 256;
    for (int i = gtid; i < n1; i += gsize) {
        float w0 = W1[i];
        unsigned short h = f2bf_u(w0);
        W1h[i] = (short)h;
        W1l[i] = (short)f2bf_u(w0 - bf2f(h));
    }
    for (int i = gtid; i < n2; i += gsize) {
        float w0 = W2[i];
        unsigned short h = f2bf_u(w0);
        W2h[i] = (short)h;
        W2l[i] = (short)f2bf_u(w0 - bf2f(h));
    }
}

__global__ void convert_count_kernel(const void* __restrict__ edges, const int* __restrict__ flag,
                                     int* __restrict__ src, int* __restrict__ dst,
                                     int* __restrict__ counts, int E) {
    int e = blockIdx.x * 256 + threadIdx.x;
    if (e >= E) return;
    int s, d;
    if (*flag) { const int* p = (const int*)edges; s = p[e]; d = p[E + e]; }
    else       { const long long* p = (const long long*)edges; s = (int)p[e]; d = (int)p[E + e]; }
    src[e] = s;
    dst[e] = d;
    atomicAdd(&counts[d], 1);
}

// per-chunk: dinv + block-sum (counts+1: self-loop edge included in CSR)
__global__ void bsum_dinv_kernel(const int* __restrict__ counts, float* __restrict__ dinv,
                                 int* __restrict__ bs, int n) {
    __shared__ int sdata[256];
    int i = blockIdx.x * 256 + threadIdx.x;
    int v = (i < n) ? counts[i] : 0;
    if (i < n) dinv[i] = rsqrtf((float)v + 1.0f);
    sdata[threadIdx.x] = (i < n) ? (v + 1) : 0;
    __syncthreads();
    #pragma unroll
    for (int off = 128; off > 0; off >>= 1) {
        if (threadIdx.x < off) sdata[threadIdx.x] += sdata[threadIdx.x + off];
        __syncthreads();
    }
    if (threadIdx.x == 0) bs[blockIdx.x] = sdata[0];
}

__global__ void scanbs_kernel(const int* __restrict__ bs, int* __restrict__ bsoff, int nb) {
    __shared__ int sdata[256];
    int tid = threadIdx.x;
    int v = (tid < nb) ? bs[tid] : 0;
    sdata[tid] = v;
    __syncthreads();
    #pragma unroll
    for (int off = 1; off < 256; off <<= 1) {
        int t = (tid >= off) ? sdata[tid - off] : 0;
        __syncthreads();
        sdata[tid] += t;
        __syncthreads();
    }
    if (tid < nb) bsoff[tid] = sdata[tid] - v;
}

// scan of (counts+1); writes rowptr, self-loop CSR record, cursor=excl+1
__global__ void scanblock_kernel(const int* __restrict__ counts, const int* __restrict__ bsoff,
                                 const float* __restrict__ dinv,
                                 int* __restrict__ rowptr, int* __restrict__ cursor,
                                 int2* __restrict__ csr, int n) {
    __shared__ int sdata[256];
    int tid = threadIdx.x;
    int i = blockIdx.x * 256 + tid;
    int v = (i < n) ? (counts[i] + 1) : 0;
    sdata[tid] = v;
    __syncthreads();
    #pragma unroll
    for (int off = 1; off < 256; off <<= 1) {
        int t = (tid >= off) ? sdata[tid - off] : 0;
        __syncthreads();
        sdata[tid] += t;
        __syncthreads();
    }
    int excl = bsoff[blockIdx.x] + sdata[tid] - v;
    if (i < n) {
        rowptr[i] = excl;
        float di = dinv[i];
        csr[excl] = make_int2(i, __builtin_bit_cast(int, di * di));  // self edge first
        cursor[i] = excl + 1;
    }
    if (i == n - 1) rowptr[n] = excl + v;
}

__global__ void fill_kernel(const int* __restrict__ src, const int* __restrict__ dst,
                            const float* __restrict__ dinv, int* __restrict__ cursor,
                            int2* __restrict__ csr, int E) {
    int e = blockIdx.x * 256 + threadIdx.x;
    if (e >= E) return;
    int s = src[e], d = dst[e];
    int pos = atomicAdd(&cursor[d], 1);
    float w = dinv[s] * dinv[d];
    csr[pos] = make_int2(s, __builtin_bit_cast(int, w));
}

// ==================================================================
// FUSED MLP: gemm1f (BM=256,BN=256,BK=32, r14 structure) + in-kernel
// GEMM2 via LDS h-buffer. No H round-trip to HBM.
//   main loop: h-acc in registers (unchanged from r14)
//   per 128-row half: waves wr==half write h (bias1+relu, bf16) into
//   LDS (unit^(row&7) swizzle, 512B row stride -> 2-way reads), then
//   all 8 waves compute z rows from LDS-h x W2(L2-hot). K-order and
//   h/l MFMA order identical to the old gemm2 -> bit-identical z.
// ==================================================================
__global__ __launch_bounds__(512)
void gemm_fused_k(const float* __restrict__ x, const short* __restrict__ Bh,
                  const short* __restrict__ Bl, const float* __restrict__ bias1,
                  const short* __restrict__ W2h, const short* __restrict__ W2l,
                  const float* __restrict__ bias2, unsigned short* __restrict__ zbf,
                  int M) {
    extern __shared__ short lds[];
    short* sA  = lds;              // [2][256*32] shorts (32 KB)
    short* sBh = lds + 16384;      // [2][256*32] (32 KB)
    short* sBl = lds + 32768;      // [2][256*32] (32 KB)
    const int KDIM = 512;
    const int tid = threadIdx.x, lane = tid & 63, wave = tid >> 6;
    const int wr = wave >> 2, wc = wave & 3;       // 2m x 4n; wave tile 128x64
    const int m0 = blockIdx.x * 256;
    const int lr = lane & 15, lk = lane >> 4;
    const int l4r = lane >> 2, l4u = lane & 3;
    const int arow = tid >> 1, ahalf = tid & 1;

    f32x4 acc[8][4];
    #pragma unroll
    for (int mi = 0; mi < 8; ++mi)
        #pragma unroll
        for (int ni = 0; ni < 4; ++ni) acc[mi][ni] = {0.f, 0.f, 0.f, 0.f};

    float4 fa[4];

    auto a_load = [&](int k0) {
        int grow = m0 + arow; if (grow > M - 1) grow = M - 1;
        const float* s = x + (size_t)grow * KDIM + k0 + ahalf * 16;
        fa[0] = ((const float4*)s)[0];
        fa[1] = ((const float4*)s)[1];
        fa[2] = ((const float4*)s)[2];
        fa[3] = ((const float4*)s)[3];
    };
    auto a_write = [&](int buf) {
        short8 s0, s1;
        s0[0] = (short)f2bf_u(fa[0].x); s0[1] = (short)f2bf_u(fa[0].y);
        s0[2] = (short)f2bf_u(fa[0].z); s0[3] = (short)f2bf_u(fa[0].w);
        s0[4] = (short)f2bf_u(fa[1].x); s0[5] = (short)f2bf_u(fa[1].y);
        s0[6] = (short)f2bf_u(fa[1].z); s0[7] = (short)f2bf_u(fa[1].w);
        s1[0] = (short)f2bf_u(fa[2].x); s1[1] = (short)f2bf_u(fa[2].y);
        s1[2] = (short)f2bf_u(fa[2].z); s1[3] = (short)f2bf_u(fa[2].w);
        s1[4] = (short)f2bf_u(fa[3].x); s1[5] = (short)f2bf_u(fa[3].y);
        s1[6] = (short)f2bf_u(fa[3].z); s1[7] = (short)f2bf_u(fa[3].w);
        int b = buf * 8192 + arow * 32;
        *reinterpret_cast<short8*>(&sA[b + (((2 * ahalf)     ^ (arow & 3)) << 3)]) = s0;
        *reinterpret_cast<short8*>(&sA[b + (((2 * ahalf + 1) ^ (arow & 3)) << 3)]) = s1;
    };
    auto b_dma = [&](int buf, int k0) {
        #pragma unroll
        for (int p = 0; p < 2; ++p) {
            int row = p * 128 + wave * 16 + l4r;
            size_t goff = (size_t)row * KDIM + k0 + ((l4u ^ (row & 3)) << 3);
            int db = buf * 8192 + (p * 128 + wave * 16) * 32;
            GLOAD_LDS16(Bh + goff, sBh + db);
            GLOAD_LDS16(Bl + goff, sBl + db);
        }
    };

    a_load(0);
    b_dma(0, 0);
    asm volatile("s_waitcnt vmcnt(0)" ::: "memory");
    a_write(0);
    __syncthreads();

    int cur = 0;
    #pragma unroll 1
    for (int t = 0; t < 16; ++t) {
        const bool pf = (t < 15);
        if (pf) {
            a_load((t + 1) * 32);
            b_dma(cur ^ 1, (t + 1) * 32);
        }
        {
            bf16x8 af[8], bhf[4], blf[4];
            #pragma unroll
            for (int mi = 0; mi < 8; ++mi) {
                int row = wr * 128 + mi * 16 + lr;
                af[mi] = *reinterpret_cast<const bf16x8*>(
                    &sA[cur * 8192 + row * 32 + ((lk ^ (row & 3)) << 3)]);
            }
            #pragma unroll
            for (int ni = 0; ni < 4; ++ni) {
                int row = wc * 64 + ni * 16 + lr;
                int idx = cur * 8192 + row * 32 + ((lk ^ (row & 3)) << 3);
                bhf[ni] = *reinterpret_cast<const bf16x8*>(&sBh[idx]);
                blf[ni] = *reinterpret_cast<const bf16x8*>(&sBl[idx]);
            }
            #pragma unroll
            for (int mi = 0; mi < 8; ++mi)
                #pragma unroll
                for (int ni = 0; ni < 4; ++ni) {
                    acc[mi][ni] = __builtin_amdgcn_mfma_f32_16x16x32_bf16(af[mi], bhf[ni], acc[mi][ni], 0, 0, 0);
                    acc[mi][ni] = __builtin_amdgcn_mfma_f32_16x16x32_bf16(af[mi], blf[ni], acc[mi][ni], 0, 0, 0);
                }
        }
        asm volatile("s_waitcnt vmcnt(0)" ::: "memory");
        if (pf) a_write(cur ^ 1);
        __syncthreads();
        cur ^= 1;
    }

    // ---- fused GEMM2 over two 128-row halves ----
    short* hbuf = lds;   // reuse: 128 rows x 256 cols bf16 = 64 KB
    #pragma unroll 1
    for (int half = 0; half < 2; ++half) {
        if (wr == half) {
            // write my 128x64 h stripe (bias1 + relu) into hbuf, swizzled
            #pragma unroll
            for (int ni = 0; ni < 4; ++ni) {
                int col = wc * 64 + ni * 16 + lr;
                float bv = bias1[col];
                int cu = col >> 3, ce = col & 7;
                #pragma unroll
                for (int mi = 0; mi < 8; ++mi) {
                    #pragma unroll
                    for (int r = 0; r < 4; ++r) {
                        int row = mi * 16 + lk * 4 + r;   // local 0..127
                        float v = fmaxf(acc[mi][ni][r] + bv, 0.0f);
                        hbuf[row * 256 + ((cu ^ (row & 7)) << 3) + ce] = (short)f2bf_u(v);
                    }
                }
            }
        }
        __syncthreads();
        // all waves: z rows half*128 + wave*16 .. +15
        {
            f32x4 zacc[4];
            #pragma unroll
            for (int ni = 0; ni < 4; ++ni) zacc[ni] = {0.f, 0.f, 0.f, 0.f};
            int lrow = wave * 16 + lr;                 // A-frag row (local)
            #pragma unroll
            for (int ks = 0; ks < 8; ++ks) {
                int kcol = ks * 32 + lk * 8;
                bf16x8 af = *reinterpret_cast<const bf16x8*>(
                    &hbuf[lrow * 256 + (((kcol >> 3) ^ (lrow & 7)) << 3)]);
                #pragma unroll
                for (int ni = 0; ni < 4; ++ni) {
                    int ocol = ni * 16 + lr;
                    bf16x8 bh = *reinterpret_cast<const bf16x8*>(W2h + ocol * 256 + kcol);
                    bf16x8 bl = *reinterpret_cast<const bf16x8*>(W2l + ocol * 256 + kcol);
                    zacc[ni] = __builtin_amdgcn_mfma_f32_16x16x32_bf16(af, bh, zacc[ni], 0, 0, 0);
                    zacc[ni] = __builtin_amdgcn_mfma_f32_16x16x32_bf16(af, bl, zacc[ni], 0, 0, 0);
                }
            }
            #pragma unroll
            for (int ni = 0; ni < 4; ++ni) {
                int col = ni * 16 + lr;
                float bv2 = bias2[col];
                #pragma unroll
                for (int r = 0; r < 4; ++r) {
                    int row = m0 + half * 128 + wave * 16 + lk * 4 + r;
                    if (row < M) zbf[(size_t)row * 64 + col] = f2bf_u(zacc[ni][r] + bv2);
                }
            }
        }
        __syncthreads();
    }
}

// ==================================================================
// Fallback tile (r10-proven). BM=128, BN=64, BK=64, 8 waves 4x2.
// ==================================================================
template<int KDIM, int LDC, bool AF32, bool RELU>
__device__ __forceinline__
void gemm_tile(const void* __restrict__ Av, const short* __restrict__ Bh,
               const short* __restrict__ Bl, const float* __restrict__ bias,
               short* __restrict__ C, int M, int m0, int n0,
               short* sAp, short* sBp) {
    constexpr int NT = KDIM / 64;
    const int tid  = threadIdx.x;
    const int lane = tid & 63;
    const int wave = tid >> 6;
    const int wr = wave >> 1, wc = wave & 1;
    const int lr = lane & 15;
    const int lk = lane >> 4;
    const int l8r = lane >> 3;
    const int l8u = lane & 7;
    const int tr = tid >> 3;
    const int tk = tid & 7;

    f32x4 acc[2][2];
    #pragma unroll
    for (int mi = 0; mi < 2; ++mi)
        #pragma unroll
        for (int ni = 0; ni < 2; ++ni) acc[mi][ni] = {0.f, 0.f, 0.f, 0.f};

    float4 fa[2][2];

    auto a_load = [&](int k0) {
        #pragma unroll
        for (int p = 0; p < 2; ++p) {
            int row = p * 64 + tr;
            int grow = m0 + row; if (grow > M - 1) grow = M - 1;
            const float* s = (const float*)Av + (size_t)grow * KDIM + k0 + tk * 8;
            fa[p][0] = *reinterpret_cast<const float4*>(s);
            fa[p][1] = *reinterpret_cast<const float4*>(s + 4);
        }
    };
    auto a_write = [&](int buf) {
        #pragma unroll
        for (int p = 0; p < 2; ++p) {
            int row = p * 64 + tr;
            short8 sh;
            sh[0] = (short)f2bf_u(fa[p][0].x); sh[1] = (short)f2bf_u(fa[p][0].y);
            sh[2] = (short)f2bf_u(fa[p][0].z); sh[3] = (short)f2bf_u(fa[p][0].w);
            sh[4] = (short)f2bf_u(fa[p][1].x); sh[5] = (short)f2bf_u(fa[p][1].y);
            sh[6] = (short)f2bf_u(fa[p][1].z); sh[7] = (short)f2bf_u(fa[p][1].w);
            *reinterpret_cast<short8*>(&sAp[buf * 8192 + row * 64 + ((tk ^ (row & 7)) << 3)]) = sh;
        }
    };
    auto a_dma = [&](int buf, int k0) {
        #pragma unroll
        for (int p = 0; p < 2; ++p) {
            int row = p * 64 + wave * 8 + l8r;
            int grow = m0 + row; if (grow > M - 1) grow = M - 1;
            const short* s = (const short*)Av + (size_t)grow * KDIM + k0 + ((l8u ^ (row & 7)) << 3);
            GLOAD_LDS16(s, sAp + buf * 8192 + p * 4096 + wave * 512);
        }
    };
    auto b_dma = [&](int buf, int k0) {
        int row = wave * 8 + l8r;
        size_t goff = (size_t)(n0 + row) * KDIM + k0 + ((l8u ^ (row & 7)) << 3);
        GLOAD_LDS16(Bh + goff, sBp + (buf * 2 + 0) * 4096 + wave * 512);
        GLOAD_LDS16(Bl + goff, sBp + (buf * 2 + 1) * 4096 + wave * 512);
    };

    if (AF32) {
        a_load(0);
        b_dma(0, 0);
        asm volatile("s_waitcnt vmcnt(0)" ::: "memory");
        a_write(0);
        __syncthreads();
    } else {
        a_dma(0, 0);
        b_dma(0, 0);
        asm volatile("s_waitcnt vmcnt(0)" ::: "memory");
        __builtin_amdgcn_s_barrier();
        asm volatile("" ::: "memory");
    }

    int cur = 0;
    #pragma unroll 1
    for (int t = 0; t < NT; ++t) {
        const bool pf = (t + 1 < NT);
        if (pf) {
            if (AF32) a_load((t + 1) * 64);
            else      a_dma(cur ^ 1, (t + 1) * 64);
            b_dma(cur ^ 1, (t + 1) * 64);
        }
        #pragma unroll
        for (int ks = 0; ks < 2; ++ks) {
            int kg = ks * 4 + lk;
            bf16x8 af[2], bhf[2], blf[2];
            #pragma unroll
            for (int mi = 0; mi < 2; ++mi) {
                int row = wr * 32 + mi * 16 + lr;
                af[mi] = *reinterpret_cast<const bf16x8*>(
                    &sAp[cur * 8192 + row * 64 + ((kg ^ (row & 7)) << 3)]);
            }
            #pragma unroll
            for (int ni = 0; ni < 2; ++ni) {
                int row = wc * 32 + ni * 16 + lr;
                int idx = row * 64 + ((kg ^ (row & 7)) << 3);
                bhf[ni] = *reinterpret_cast<const bf16x8*>(&sBp[(cur * 2 + 0) * 4096 + idx]);
                blf[ni] = *reinterpret_cast<const bf16x8*>(&sBp[(cur * 2 + 1) * 4096 + idx]);
            }
            #pragma unroll
            for (int mi = 0; mi < 2; ++mi)
                #pragma unroll
                for (int ni = 0; ni < 2; ++ni) {
                    acc[mi][ni] = __builtin_amdgcn_mfma_f32_16x16x32_bf16(af[mi], bhf[ni], acc[mi][ni], 0, 0, 0);
                    acc[mi][ni] = __builtin_amdgcn_mfma_f32_16x16x32_bf16(af[mi], blf[ni], acc[mi][ni], 0, 0, 0);
                }
        }
        asm volatile("s_waitcnt vmcnt(0)" ::: "memory");
        if (AF32) { if (pf) a_write(cur ^ 1); __syncthreads(); }
        else { __builtin_amdgcn_s_barrier(); asm volatile("" ::: "memory"); }
        cur ^= 1;
    }

    #pragma unroll
    for (int ni = 0; ni < 2; ++ni) {
        int col = n0 + wc * 32 + ni * 16 + lr;
        float bv = bias[col];
        #pragma unroll
        for (int mi = 0; mi < 2; ++mi) {
            #pragma unroll
            for (int r = 0; r < 4; ++r) {
                int row = m0 + wr * 32 + mi * 16 + lk * 4 + r;
                if (row < M) {
                    float v = acc[mi][ni][r] + bv;
                    if (RELU) v = fmaxf(v, 0.0f);
                    C[(size_t)row * LDC + col] = (short)f2bf_u(v);
                }
            }
        }
    }
}

__global__ __launch_bounds__(512)
void gemm1_k(const float* __restrict__ x, const short* __restrict__ W1h,
             const short* __restrict__ W1l, const float* __restrict__ b1,
             short* __restrict__ Hbf, int M) {
    __shared__ short sAp[2 * 128 * 64];
    __shared__ short sBp[2 * 2 * 64 * 64];
    int t = blockIdx.x;
    gemm_tile<512, 256, true, true>(x, W1h, W1l, b1, Hbf, M, (t >> 2) * 128, (t & 3) * 64, sAp, sBp);
}

__global__ __launch_bounds__(512)
void gemm2_k(const short* __restrict__ Hbf, const short* __restrict__ W2h,
             const short* __restrict__ W2l, const float* __restrict__ b2,
             short* __restrict__ zbf, int M) {
    __shared__ short sAp[2 * 128 * 64];
    __shared__ short sBp[2 * 2 * 64 * 64];
    gemm_tile<256, 64, false, false>(Hbf, W2h, W2l, b2, zbf, M, blockIdx.x * 128, 0, sAp, sBp);
}

// ==================================================================
// Propagation v5 (r17-proven): grid-stride 2048 blocks; one wave/node;
// scalar csr via readfirstlane; 8-deep gather; self-edge CSR.
// ==================================================================
__global__ __launch_bounds__(256)
void prop_step(const unsigned short* __restrict__ hin, const unsigned short* __restrict__ zbf,
               const int* __restrict__ rowptr, const int2* __restrict__ csr,
               void* __restrict__ hout, int outf32, int n) {
    const int lane = threadIdx.x & 63;
    const int nwaves = gridDim.x * 4;
    for (int node = blockIdx.x * 4 + (threadIdx.x >> 6); node < n; node += nwaves) {
        int base = node << 6;
        float acc = 0.0f;
        int e  = __builtin_amdgcn_readfirstlane(rowptr[node]);
        int e1 = __builtin_amdgcn_readfirstlane(rowptr[node + 1]);

        for (; e + 8 <= e1; e += 8) {
            int2 r[8]; unsigned short v[8];
            #pragma unroll
            for (int j = 0; j < 8; ++j) r[j] = csr[e + j];
            #pragma unroll
            for (int j = 0; j < 8; ++j) v[j] = hin[((unsigned)r[j].x << 6) + lane];
            #pragma unroll
            for (int j = 0; j < 8; ++j) acc = fmaf(bf2f(v[j]), i2f(r[j].y), acc);
        }
        for (; e + 4 <= e1; e += 4) {
            int2 r[4]; unsigned short v[4];
            #pragma unroll
            for (int j = 0; j < 4; ++j) r[j] = csr[e + j];
            #pragma unroll
            for (int j = 0; j < 4; ++j) v[j] = hin[((unsigned)r[j].x << 6) + lane];
            #pragma unroll
            for (int j = 0; j < 4; ++j) acc = fmaf(bf2f(v[j]), i2f(r[j].y), acc);
        }
        for (; e < e1; ++e) {
            int2 r = csr[e];
            acc = fmaf(bf2f(hin[((unsigned)r.x << 6) + lane]), i2f(r.y), acc);
        }

        float res = 0.9f * acc + 0.1f * bf2f(zbf[base + lane]);
        if (outf32) ((float*)hout)[base + lane] = res;
        else        ((unsigned short*)hout)[base + lane] = f2bf_u(res);
    }
}

// ==================================================================
extern "C" void kernel_launch(void* const* d_in, const int* in_sizes, int n_in,
                              void* d_out, int out_size, void* d_ws, size_t ws_size,
                              hipStream_t stream) {
    const float* x  = (const float*)d_in[0];
    const void*  ei = d_in[1];
    const float* W1 = (const float*)d_in[2];
    const float* b1 = (const float*)d_in[3];
    const float* W2 = (const float*)d_in[4];
    const float* b2 = (const float*)d_in[5];
    float* dout = (float*)d_out;

    const int IN_C = 512, HID_C = 256, OUT_C = 64, Ksteps = 10;
    const int N = in_sizes[0] / IN_C;   // 50000
    const int E = in_sizes[1] / 2;      // 800000

    char* w = (char*)d_ws;
    auto alloc = [&](size_t bytes) { char* p = w; w += (bytes + 255) & ~(size_t)255; return p; };
    int*   flag    = (int*)  alloc(4);
    int*   src32   = (int*)  alloc((size_t)E * 4);
    int*   dst32   = (int*)  alloc((size_t)E * 4);
    int*   counts  = (int*)  alloc((size_t)N * 4);
    int*   rowptr  = (int*)  alloc((size_t)(N + 1) * 4);
    int*   cursor  = (int*)  alloc((size_t)N * 4);
    float* dinv    = (float*)alloc((size_t)N * 4);
    int2*  csr     = (int2*) alloc((size_t)(E + N) * 8);   // +N self edges
    short* W1h     = (short*)alloc((size_t)HID_C * IN_C * 2);
    short* W1l     = (short*)alloc((size_t)HID_C * IN_C * 2);
    short* W2h     = (short*)alloc((size_t)OUT_C * HID_C * 2);
    short* W2l     = (short*)alloc((size_t)OUT_C * HID_C * 2);
    short* Hbf     = (short*)alloc((size_t)N * HID_C * 2);   // fallback path only
    unsigned short* zbf = (unsigned short*)alloc((size_t)N * OUT_C * 2);
    unsigned short* hA  = (unsigned short*)alloc((size_t)N * OUT_C * 2);
    unsigned short* hB  = (unsigned short*)alloc((size_t)N * OUT_C * 2);
    int*   bs      = (int*)  alloc(256 * 4);
    int*   bsoff   = (int*)  alloc(256 * 4);

    const int egrid = (E + 255) / 256;
    const int nblk = (N + 255) / 256;

    // preprocessing (6 dispatches, no memsets)
    prep_a<<<512, 256, 0, stream>>>(ei, W1, W2, flag, W1h, W1l, W2h, W2l, counts, N);
    convert_count_kernel<<<egrid, 256, 0, stream>>>(ei, flag, src32, dst32, counts, E);
    bsum_dinv_kernel<<<nblk, 256, 0, stream>>>(counts, dinv, bs, N);
    scanbs_kernel<<<1, 256, 0, stream>>>(bs, bsoff, nblk);
    scanblock_kernel<<<nblk, 256, 0, stream>>>(counts, bsoff, dinv, rowptr, cursor, csr, N);
    fill_kernel<<<egrid, 256, 0, stream>>>(src32, dst32, dinv, cursor, csr, E);

    // FUSED MLP (gemm1 + gemm2 in one kernel, 96 KB dynamic LDS); fallback r10
    constexpr int G1_LDS = 98304;
    const int g1grid = (N + 255) / 256;
    bool big = hipFuncSetAttribute((const void*)gemm_fused_k,
                                   hipFuncAttributeMaxDynamicSharedMemorySize,
                                   G1_LDS) == hipSuccess;
    if (big) {
        gemm_fused_k<<<g1grid, 512, G1_LDS, stream>>>(x, W1h, W1l, b1, W2h, W2l, b2, zbf, N);
        if (hipGetLastError() != hipSuccess) big = false;
    }
    if (!big) {
        gemm1_k<<<((N + 127) / 128) * 4, 512, 0, stream>>>(x, W1h, W1l, b1, Hbf, N);
        gemm2_k<<<(N + 127) / 128, 512, 0, stream>>>(Hbf, W2h, W2l, b2, (short*)zbf, N);
    }

    // propagation: grid-stride 2048 blocks; h^(0)=z in zbf; ping-pong hA/hB;
    // last step writes fp32 dout
    const unsigned short* pin = zbf;
    for (int s = 0; s < Ksteps; ++s) {
        bool last = (s == Ksteps - 1);
        void* out = last ? (void*)dout : ((s & 1) ? (void*)hB : (void*)hA);
        prop_step<<<2048, 256, 0, stream>>>(pin, zbf, rowptr, csr,
                                            out, last ? 1 : 0, N);
        pin = (const unsigned short*)out;
    }
}

// Round 19
// 376.802 us; speedup vs baseline: 1.2253x; 1.2253x over previous
//
#include <hip/hip_runtime.h>

typedef __bf16 bf16x8 __attribute__((ext_vector_type(8)));
typedef float f32x4 __attribute__((ext_vector_type(4)));
typedef short short8 __attribute__((ext_vector_type(8)));

__device__ __forceinline__ unsigned short f2bf_u(float f) {
    unsigned u = __builtin_bit_cast(unsigned, f);
    u += 0x7FFFu + ((u >> 16) & 1u);   // RNE
    return (unsigned short)(u >> 16);
}
__device__ __forceinline__ float bf2f(unsigned short h) {
    unsigned u = ((unsigned)h) << 16;
    return __builtin_bit_cast(float, u);
}
__device__ __forceinline__ float i2f(int b) { return __builtin_bit_cast(float, b); }

#define GLOAD_LDS16(gsrc, ldst)                                                        \
    __builtin_amdgcn_global_load_lds((const __attribute__((address_space(1))) void*)(gsrc), \
                                     (__attribute__((address_space(3))) void*)(ldst), 16, 0, 0)

// ==================================================================
// prep_a: flag init+detect (block 0), counts zeroing, weight splits.
// ==================================================================
__global__ __launch_bounds__(256)
void prep_a(const void* __restrict__ ei, const float* __restrict__ W1,
            const float* __restrict__ W2, int* __restrict__ flag,
            short* __restrict__ W1h, short* __restrict__ W1l,
            short* __restrict__ W2h, short* __restrict__ W2l,
            int* __restrict__ counts, int N) {
    __shared__ int sflag;
    const int tid = threadIdx.x;
    const int gtid = blockIdx.x * 256 + tid;
    const int gsize = gridDim.x * 256;
    if (blockIdx.x == 0) {
        if (tid == 0) sflag = 0;
        __syncthreads();
        unsigned v = 0;
        for (int i = tid * 2 + 1; i < 2048; i += 512) v |= ((const unsigned*)ei)[i];
        if (v) atomicOr(&sflag, 1);
        __syncthreads();
        if (tid == 0) *flag = sflag;   // nonzero odd words => int32 input
    }
    for (int i = gtid; i < N; i += gsize) counts[i] = 0;
    const int n1 = 256 * 512, n2 = 64 * 256;
    for (int i = gtid; i < n1; i += gsize) {
        float w0 = W1[i];
        unsigned short h = f2bf_u(w0);
        W1h[i] = (short)h;
        W1l[i] = (short)f2bf_u(w0 - bf2f(h));
    }
    for (int i = gtid; i < n2; i += gsize) {
        float w0 = W2[i];
        unsigned short h = f2bf_u(w0);
        W2h[i] = (short)h;
        W2l[i] = (short)f2bf_u(w0 - bf2f(h));
    }
}

__global__ void convert_count_kernel(const void* __restrict__ edges, const int* __restrict__ flag,
                                     int* __restrict__ src, int* __restrict__ dst,
                                     int* __restrict__ counts, int E) {
    int e = blockIdx.x * 256 + threadIdx.x;
    if (e >= E) return;
    int s, d;
    if (*flag) { const int* p = (const int*)edges; s = p[e]; d = p[E + e]; }
    else       { const long long* p = (const long long*)edges; s = (int)p[e]; d = (int)p[E + e]; }
    src[e] = s;
    dst[e] = d;
    atomicAdd(&counts[d], 1);
}

// per-chunk: dinv + block-sum (counts+1: self-loop edge included in CSR)
__global__ void bsum_dinv_kernel(const int* __restrict__ counts, float* __restrict__ dinv,
                                 int* __restrict__ bs, int n) {
    __shared__ int sdata[256];
    int i = blockIdx.x * 256 + threadIdx.x;
    int v = (i < n) ? counts[i] : 0;
    if (i < n) dinv[i] = rsqrtf((float)v + 1.0f);
    sdata[threadIdx.x] = (i < n) ? (v + 1) : 0;
    __syncthreads();
    #pragma unroll
    for (int off = 128; off > 0; off >>= 1) {
        if (threadIdx.x < off) sdata[threadIdx.x] += sdata[threadIdx.x + off];
        __syncthreads();
    }
    if (threadIdx.x == 0) bs[blockIdx.x] = sdata[0];
}

__global__ void scanbs_kernel(const int* __restrict__ bs, int* __restrict__ bsoff, int nb) {
    __shared__ int sdata[256];
    int tid = threadIdx.x;
    int v = (tid < nb) ? bs[tid] : 0;
    sdata[tid] = v;
    __syncthreads();
    #pragma unroll
    for (int off = 1; off < 256; off <<= 1) {
        int t = (tid >= off) ? sdata[tid - off] : 0;
        __syncthreads();
        sdata[tid] += t;
        __syncthreads();
    }
    if (tid < nb) bsoff[tid] = sdata[tid] - v;
}

// scan of (counts+1); writes rowptr, self-loop CSR record, cursor=excl+1
__global__ void scanblock_kernel(const int* __restrict__ counts, const int* __restrict__ bsoff,
                                 const float* __restrict__ dinv,
                                 int* __restrict__ rowptr, int* __restrict__ cursor,
                                 int2* __restrict__ csr, int n) {
    __shared__ int sdata[256];
    int tid = threadIdx.x;
    int i = blockIdx.x * 256 + tid;
    int v = (i < n) ? (counts[i] + 1) : 0;
    sdata[tid] = v;
    __syncthreads();
    #pragma unroll
    for (int off = 1; off < 256; off <<= 1) {
        int t = (tid >= off) ? sdata[tid - off] : 0;
        __syncthreads();
        sdata[tid] += t;
        __syncthreads();
    }
    int excl = bsoff[blockIdx.x] + sdata[tid] - v;
    if (i < n) {
        rowptr[i] = excl;
        float di = dinv[i];
        csr[excl] = make_int2(i, __builtin_bit_cast(int, di * di));  // self edge first
        cursor[i] = excl + 1;
    }
    if (i == n - 1) rowptr[n] = excl + v;
}

__global__ void fill_kernel(const int* __restrict__ src, const int* __restrict__ dst,
                            const float* __restrict__ dinv, int* __restrict__ cursor,
                            int2* __restrict__ csr, int E) {
    int e = blockIdx.x * 256 + threadIdx.x;
    if (e >= E) return;
    int s = src[e], d = dst[e];
    int pos = atomicAdd(&cursor[d], 1);
    float w = dinv[s] * dinv[d];
    csr[pos] = make_int2(s, __builtin_bit_cast(int, w));
}

// ==================================================================
// gemm1f v2 (r14/r17-proven best): BM=256, BN=256, BK=32, 512 thr
// (8 waves, 2m x 4n), 96 KB dynamic LDS, grid = 196 blocks (one round).
// ==================================================================
__global__ __launch_bounds__(512)
void gemm1f_k(const float* __restrict__ x, const short* __restrict__ Bh,
              const short* __restrict__ Bl, const float* __restrict__ bias,
              short* __restrict__ C, int M) {
    extern __shared__ short lds[];
    short* sA  = lds;              // [2][256*32] shorts (32 KB)
    short* sBh = lds + 16384;      // [2][256*32] (32 KB)
    short* sBl = lds + 32768;      // [2][256*32] (32 KB)
    const int KDIM = 512, LDC = 256;
    const int tid = threadIdx.x, lane = tid & 63, wave = tid >> 6;
    const int wr = wave >> 2, wc = wave & 3;       // 2m x 4n; wave tile 128x64
    const int m0 = blockIdx.x * 256;
    const int lr = lane & 15, lk = lane >> 4;
    const int l4r = lane >> 2, l4u = lane & 3;
    const int arow = tid >> 1, ahalf = tid & 1;

    f32x4 acc[8][4];
    #pragma unroll
    for (int mi = 0; mi < 8; ++mi)
        #pragma unroll
        for (int ni = 0; ni < 4; ++ni) acc[mi][ni] = {0.f, 0.f, 0.f, 0.f};

    float4 fa[4];

    auto a_load = [&](int k0) {
        int grow = m0 + arow; if (grow > M - 1) grow = M - 1;
        const float* s = x + (size_t)grow * KDIM + k0 + ahalf * 16;
        fa[0] = ((const float4*)s)[0];
        fa[1] = ((const float4*)s)[1];
        fa[2] = ((const float4*)s)[2];
        fa[3] = ((const float4*)s)[3];
    };
    auto a_write = [&](int buf) {
        short8 s0, s1;
        s0[0] = (short)f2bf_u(fa[0].x); s0[1] = (short)f2bf_u(fa[0].y);
        s0[2] = (short)f2bf_u(fa[0].z); s0[3] = (short)f2bf_u(fa[0].w);
        s0[4] = (short)f2bf_u(fa[1].x); s0[5] = (short)f2bf_u(fa[1].y);
        s0[6] = (short)f2bf_u(fa[1].z); s0[7] = (short)f2bf_u(fa[1].w);
        s1[0] = (short)f2bf_u(fa[2].x); s1[1] = (short)f2bf_u(fa[2].y);
        s1[2] = (short)f2bf_u(fa[2].z); s1[3] = (short)f2bf_u(fa[2].w);
        s1[4] = (short)f2bf_u(fa[3].x); s1[5] = (short)f2bf_u(fa[3].y);
        s1[6] = (short)f2bf_u(fa[3].z); s1[7] = (short)f2bf_u(fa[3].w);
        int b = buf * 8192 + arow * 32;
        *reinterpret_cast<short8*>(&sA[b + (((2 * ahalf)     ^ (arow & 3)) << 3)]) = s0;
        *reinterpret_cast<short8*>(&sA[b + (((2 * ahalf + 1) ^ (arow & 3)) << 3)]) = s1;
    };
    auto b_dma = [&](int buf, int k0) {
        #pragma unroll
        for (int p = 0; p < 2; ++p) {
            int row = p * 128 + wave * 16 + l4r;
            size_t goff = (size_t)row * KDIM + k0 + ((l4u ^ (row & 3)) << 3);
            int db = buf * 8192 + (p * 128 + wave * 16) * 32;
            GLOAD_LDS16(Bh + goff, sBh + db);
            GLOAD_LDS16(Bl + goff, sBl + db);
        }
    };

    a_load(0);
    b_dma(0, 0);
    asm volatile("s_waitcnt vmcnt(0)" ::: "memory");
    a_write(0);
    __syncthreads();

    int cur = 0;
    #pragma unroll 1
    for (int t = 0; t < 16; ++t) {
        const bool pf = (t < 15);
        if (pf) {
            a_load((t + 1) * 32);
            b_dma(cur ^ 1, (t + 1) * 32);
        }
        {
            bf16x8 af[8], bhf[4], blf[4];
            #pragma unroll
            for (int mi = 0; mi < 8; ++mi) {
                int row = wr * 128 + mi * 16 + lr;
                af[mi] = *reinterpret_cast<const bf16x8*>(
                    &sA[cur * 8192 + row * 32 + ((lk ^ (row & 3)) << 3)]);
            }
            #pragma unroll
            for (int ni = 0; ni < 4; ++ni) {
                int row = wc * 64 + ni * 16 + lr;
                int idx = cur * 8192 + row * 32 + ((lk ^ (row & 3)) << 3);
                bhf[ni] = *reinterpret_cast<const bf16x8*>(&sBh[idx]);
                blf[ni] = *reinterpret_cast<const bf16x8*>(&sBl[idx]);
            }
            #pragma unroll
            for (int mi = 0; mi < 8; ++mi)
                #pragma unroll
                for (int ni = 0; ni < 4; ++ni) {
                    acc[mi][ni] = __builtin_amdgcn_mfma_f32_16x16x32_bf16(af[mi], bhf[ni], acc[mi][ni], 0, 0, 0);
                    acc[mi][ni] = __builtin_amdgcn_mfma_f32_16x16x32_bf16(af[mi], blf[ni], acc[mi][ni], 0, 0, 0);
                }
        }
        asm volatile("s_waitcnt vmcnt(0)" ::: "memory");
        if (pf) a_write(cur ^ 1);
        __syncthreads();
        cur ^= 1;
    }

    #pragma unroll
    for (int ni = 0; ni < 4; ++ni) {
        int col = wc * 64 + ni * 16 + lr;
        float bv = bias[col];
        #pragma unroll
        for (int mi = 0; mi < 8; ++mi) {
            #pragma unroll
            for (int r = 0; r < 4; ++r) {
                int row = m0 + wr * 128 + mi * 16 + lk * 4 + r;
                if (row < M) {
                    float v = fmaxf(acc[mi][ni][r] + bv, 0.0f);
                    C[(size_t)row * LDC + col] = (short)f2bf_u(v);
                }
            }
        }
    }
}

// ==================================================================
// Fallback / gemm2 tile (r10-proven). BM=128, BN=64, BK=64, 8 waves 4x2.
// ==================================================================
template<int KDIM, int LDC, bool AF32, bool RELU>
__device__ __forceinline__
void gemm_tile(const void* __restrict__ Av, const short* __restrict__ Bh,
               const short* __restrict__ Bl, const float* __restrict__ bias,
               short* __restrict__ C, int M, int m0, int n0,
               short* sAp, short* sBp) {
    constexpr int NT = KDIM / 64;
    const int tid  = threadIdx.x;
    const int lane = tid & 63;
    const int wave = tid >> 6;
    const int wr = wave >> 1, wc = wave & 1;
    const int lr = lane & 15;
    const int lk = lane >> 4;
    const int l8r = lane >> 3;
    const int l8u = lane & 7;
    const int tr = tid >> 3;
    const int tk = tid & 7;

    f32x4 acc[2][2];
    #pragma unroll
    for (int mi = 0; mi < 2; ++mi)
        #pragma unroll
        for (int ni = 0; ni < 2; ++ni) acc[mi][ni] = {0.f, 0.f, 0.f, 0.f};

    float4 fa[2][2];

    auto a_load = [&](int k0) {
        #pragma unroll
        for (int p = 0; p < 2; ++p) {
            int row = p * 64 + tr;
            int grow = m0 + row; if (grow > M - 1) grow = M - 1;
            const float* s = (const float*)Av + (size_t)grow * KDIM + k0 + tk * 8;
            fa[p][0] = *reinterpret_cast<const float4*>(s);
            fa[p][1] = *reinterpret_cast<const float4*>(s + 4);
        }
    };
    auto a_write = [&](int buf) {
        #pragma unroll
        for (int p = 0; p < 2; ++p) {
            int row = p * 64 + tr;
            short8 sh;
            sh[0] = (short)f2bf_u(fa[p][0].x); sh[1] = (short)f2bf_u(fa[p][0].y);
            sh[2] = (short)f2bf_u(fa[p][0].z); sh[3] = (short)f2bf_u(fa[p][0].w);
            sh[4] = (short)f2bf_u(fa[p][1].x); sh[5] = (short)f2bf_u(fa[p][1].y);
            sh[6] = (short)f2bf_u(fa[p][1].z); sh[7] = (short)f2bf_u(fa[p][1].w);
            *reinterpret_cast<short8*>(&sAp[buf * 8192 + row * 64 + ((tk ^ (row & 7)) << 3)]) = sh;
        }
    };
    auto a_dma = [&](int buf, int k0) {
        #pragma unroll
        for (int p = 0; p < 2; ++p) {
            int row = p * 64 + wave * 8 + l8r;
            int grow = m0 + row; if (grow > M - 1) grow = M - 1;
            const short* s = (const short*)Av + (size_t)grow * KDIM + k0 + ((l8u ^ (row & 7)) << 3);
            GLOAD_LDS16(s, sAp + buf * 8192 + p * 4096 + wave * 512);
        }
    };
    auto b_dma = [&](int buf, int k0) {
        int row = wave * 8 + l8r;
        size_t goff = (size_t)(n0 + row) * KDIM + k0 + ((l8u ^ (row & 7)) << 3);
        GLOAD_LDS16(Bh + goff, sBp + (buf * 2 + 0) * 4096 + wave * 512);
        GLOAD_LDS16(Bl + goff, sBp + (buf * 2 + 1) * 4096 + wave * 512);
    };

    if (AF32) {
        a_load(0);
        b_dma(0, 0);
        asm volatile("s_waitcnt vmcnt(0)" ::: "memory");
        a_write(0);
        __syncthreads();
    } else {
        a_dma(0, 0);
        b_dma(0, 0);
        asm volatile("s_waitcnt vmcnt(0)" ::: "memory");
        __builtin_amdgcn_s_barrier();
        asm volatile("" ::: "memory");
    }

    int cur = 0;
    #pragma unroll 1
    for (int t = 0; t < NT; ++t) {
        const bool pf = (t + 1 < NT);
        if (pf) {
            if (AF32) a_load((t + 1) * 64);
            else      a_dma(cur ^ 1, (t + 1) * 64);
            b_dma(cur ^ 1, (t + 1) * 64);
        }
        #pragma unroll
        for (int ks = 0; ks < 2; ++ks) {
            int kg = ks * 4 + lk;
            bf16x8 af[2], bhf[2], blf[2];
            #pragma unroll
            for (int mi = 0; mi < 2; ++mi) {
                int row = wr * 32 + mi * 16 + lr;
                af[mi] = *reinterpret_cast<const bf16x8*>(
                    &sAp[cur * 8192 + row * 64 + ((kg ^ (row & 7)) << 3)]);
            }
            #pragma unroll
            for (int ni = 0; ni < 2; ++ni) {
                int row = wc * 32 + ni * 16 + lr;
                int idx = row * 64 + ((kg ^ (row & 7)) << 3);
                bhf[ni] = *reinterpret_cast<const bf16x8*>(&sBp[(cur * 2 + 0) * 4096 + idx]);
                blf[ni] = *reinterpret_cast<const bf16x8*>(&sBp[(cur * 2 + 1) * 4096 + idx]);
            }
            #pragma unroll
            for (int mi = 0; mi < 2; ++mi)
                #pragma unroll
                for (int ni = 0; ni < 2; ++ni) {
                    acc[mi][ni] = __builtin_amdgcn_mfma_f32_16x16x32_bf16(af[mi], bhf[ni], acc[mi][ni], 0, 0, 0);
                    acc[mi][ni] = __builtin_amdgcn_mfma_f32_16x16x32_bf16(af[mi], blf[ni], acc[mi][ni], 0, 0, 0);
                }
        }
        asm volatile("s_waitcnt vmcnt(0)" ::: "memory");
        if (AF32) { if (pf) a_write(cur ^ 1); __syncthreads(); }
        else { __builtin_amdgcn_s_barrier(); asm volatile("" ::: "memory"); }
        cur ^= 1;
    }

    #pragma unroll
    for (int ni = 0; ni < 2; ++ni) {
        int col = n0 + wc * 32 + ni * 16 + lr;
        float bv = bias[col];
        #pragma unroll
        for (int mi = 0; mi < 2; ++mi) {
            #pragma unroll
            for (int r = 0; r < 4; ++r) {
                int row = m0 + wr * 32 + mi * 16 + lk * 4 + r;
                if (row < M) {
                    float v = acc[mi][ni][r] + bv;
                    if (RELU) v = fmaxf(v, 0.0f);
                    C[(size_t)row * LDC + col] = (short)f2bf_u(v);
                }
            }
        }
    }
}

__global__ __launch_bounds__(512)
void gemm1_k(const float* __restrict__ x, const short* __restrict__ W1h,
             const short* __restrict__ W1l, const float* __restrict__ b1,
             short* __restrict__ Hbf, int M) {
    __shared__ short sAp[2 * 128 * 64];
    __shared__ short sBp[2 * 2 * 64 * 64];
    int t = blockIdx.x;
    gemm_tile<512, 256, true, true>(x, W1h, W1l, b1, Hbf, M, (t >> 2) * 128, (t & 3) * 64, sAp, sBp);
}

__global__ __launch_bounds__(512)
void gemm2_k(const short* __restrict__ Hbf, const short* __restrict__ W2h,
             const short* __restrict__ W2l, const float* __restrict__ b2,
             short* __restrict__ zbf, int M) {
    __shared__ short sAp[2 * 128 * 64];
    __shared__ short sBp[2 * 2 * 64 * 64];
    gemm_tile<256, 64, false, false>(Hbf, W2h, W2l, b2, zbf, M, blockIdx.x * 128, 0, sAp, sBp);
}

// ==================================================================
// Propagation v5 (r17-proven): grid-stride 2048 blocks; one wave/node;
// scalar csr via readfirstlane; 8-deep gather; self-edge CSR.
// ==================================================================
__global__ __launch_bounds__(256)
void prop_step(const unsigned short* __restrict__ hin, const unsigned short* __restrict__ zbf,
               const int* __restrict__ rowptr, const int2* __restrict__ csr,
               void* __restrict__ hout, int outf32, int n) {
    const int lane = threadIdx.x & 63;
    const int nwaves = gridDim.x * 4;
    for (int node = blockIdx.x * 4 + (threadIdx.x >> 6); node < n; node += nwaves) {
        int base = node << 6;
        float acc = 0.0f;
        int e  = __builtin_amdgcn_readfirstlane(rowptr[node]);
        int e1 = __builtin_amdgcn_readfirstlane(rowptr[node + 1]);

        for (; e + 8 <= e1; e += 8) {
            int2 r[8]; unsigned short v[8];
            #pragma unroll
            for (int j = 0; j < 8; ++j) r[j] = csr[e + j];
            #pragma unroll
            for (int j = 0; j < 8; ++j) v[j] = hin[((unsigned)r[j].x << 6) + lane];
            #pragma unroll
            for (int j = 0; j < 8; ++j) acc = fmaf(bf2f(v[j]), i2f(r[j].y), acc);
        }
        for (; e + 4 <= e1; e += 4) {
            int2 r[4]; unsigned short v[4];
            #pragma unroll
            for (int j = 0; j < 4; ++j) r[j] = csr[e + j];
            #pragma unroll
            for (int j = 0; j < 4; ++j) v[j] = hin[((unsigned)r[j].x << 6) + lane];
            #pragma unroll
            for (int j = 0; j < 4; ++j) acc = fmaf(bf2f(v[j]), i2f(r[j].y), acc);
        }
        for (; e < e1; ++e) {
            int2 r = csr[e];
            acc = fmaf(bf2f(hin[((unsigned)r.x << 6) + lane]), i2f(r.y), acc);
        }

        float res = 0.9f * acc + 0.1f * bf2f(zbf[base + lane]);
        if (outf32) ((float*)hout)[base + lane] = res;
        else        ((unsigned short*)hout)[base + lane] = f2bf_u(res);
    }
}

// ==================================================================
extern "C" void kernel_launch(void* const* d_in, const int* in_sizes, int n_in,
                              void* d_out, int out_size, void* d_ws, size_t ws_size,
                              hipStream_t stream) {
    const float* x  = (const float*)d_in[0];
    const void*  ei = d_in[1];
    const float* W1 = (const float*)d_in[2];
    const float* b1 = (const float*)d_in[3];
    const float* W2 = (const float*)d_in[4];
    const float* b2 = (const float*)d_in[5];
    float* dout = (float*)d_out;

    const int IN_C = 512, HID_C = 256, OUT_C = 64, Ksteps = 10;
    const int N = in_sizes[0] / IN_C;   // 50000
    const int E = in_sizes[1] / 2;      // 800000

    char* w = (char*)d_ws;
    auto alloc = [&](size_t bytes) { char* p = w; w += (bytes + 255) & ~(size_t)255; return p; };
    int*   flag    = (int*)  alloc(4);
    int*   src32   = (int*)  alloc((size_t)E * 4);
    int*   dst32   = (int*)  alloc((size_t)E * 4);
    int*   counts  = (int*)  alloc((size_t)N * 4);
    int*   rowptr  = (int*)  alloc((size_t)(N + 1) * 4);
    int*   cursor  = (int*)  alloc((size_t)N * 4);
    float* dinv    = (float*)alloc((size_t)N * 4);
    int2*  csr     = (int2*) alloc((size_t)(E + N) * 8);   // +N self edges
    short* W1h     = (short*)alloc((size_t)HID_C * IN_C * 2);
    short* W1l     = (short*)alloc((size_t)HID_C * IN_C * 2);
    short* W2h     = (short*)alloc((size_t)OUT_C * HID_C * 2);
    short* W2l     = (short*)alloc((size_t)OUT_C * HID_C * 2);
    short* Hbf     = (short*)alloc((size_t)N * HID_C * 2);
    unsigned short* zbf = (unsigned short*)alloc((size_t)N * OUT_C * 2);
    unsigned short* hA  = (unsigned short*)alloc((size_t)N * OUT_C * 2);
    unsigned short* hB  = (unsigned short*)alloc((size_t)N * OUT_C * 2);
    int*   bs      = (int*)  alloc(256 * 4);
    int*   bsoff   = (int*)  alloc(256 * 4);

    const int egrid = (E + 255) / 256;
    const int nblk = (N + 255) / 256;

    // preprocessing (6 dispatches, no memsets)
    prep_a<<<512, 256, 0, stream>>>(ei, W1, W2, flag, W1h, W1l, W2h, W2l, counts, N);
    convert_count_kernel<<<egrid, 256, 0, stream>>>(ei, flag, src32, dst32, counts, E);
    bsum_dinv_kernel<<<nblk, 256, 0, stream>>>(counts, dinv, bs, N);
    scanbs_kernel<<<1, 256, 0, stream>>>(bs, bsoff, nblk);
    scanblock_kernel<<<nblk, 256, 0, stream>>>(counts, bsoff, dinv, rowptr, cursor, csr, N);
    fill_kernel<<<egrid, 256, 0, stream>>>(src32, dst32, dinv, cursor, csr, E);

    // GEMM1: BM=256/BN=256/BK=32, 96 KB dynamic LDS (r14 best); fallback r10
    constexpr int G1_LDS = 98304;
    const int g1grid = (N + 255) / 256;
    bool big = hipFuncSetAttribute((const void*)gemm1f_k,
                                   hipFuncAttributeMaxDynamicSharedMemorySize,
                                   G1_LDS) == hipSuccess;
    if (big) {
        gemm1f_k<<<g1grid, 512, G1_LDS, stream>>>(x, W1h, W1l, b1, Hbf, N);
        if (hipGetLastError() != hipSuccess) big = false;
    }
    if (!big) {
        gemm1_k<<<((N + 127) / 128) * 4, 512, 0, stream>>>(x, W1h, W1l, b1, Hbf, N);
    }
    gemm2_k<<<(N + 127) / 128, 512, 0, stream>>>(Hbf, W2h, W2l, b2, (short*)zbf, N);

    // propagation: grid-stride 2048 blocks; h^(0)=z in zbf; ping-pong hA/hB;
    // last step writes fp32 dout
    const unsigned short* pin = zbf;
    for (int s = 0; s < Ksteps; ++s) {
        bool last = (s == Ksteps - 1);
        void* out = last ? (void*)dout : ((s & 1) ? (void*)hB : (void*)hA);
        prop_step<<<2048, 256, 0, stream>>>(pin, zbf, rowptr, csr,
                                            out, last ? 1 : 0, N);
        pin = (const unsigned short*)out;
    }
}

// Round 20
// 374.618 us; speedup vs baseline: 1.2324x; 1.0058x over previous
//
#include <hip/hip_runtime.h>

typedef __bf16 bf16x8 __attribute__((ext_vector_type(8)));
typedef float f32x4 __attribute__((ext_vector_type(4)));
typedef short short8 __attribute__((ext_vector_type(8)));

__device__ __forceinline__ unsigned short f2bf_u(float f) {
    unsigned u = __builtin_bit_cast(unsigned, f);
    u += 0x7FFFu + ((u >> 16) & 1u);   // RNE
    return (unsigned short)(u >> 16);
}
__device__ __forceinline__ float bf2f(unsigned short h) {
    unsigned u = ((unsigned)h) << 16;
    return __builtin_bit_cast(float, u);
}
__device__ __forceinline__ float i2f(int b) { return __builtin_bit_cast(float, b); }

#define GLOAD_LDS16(gsrc, ldst)                                                        \
    __builtin_amdgcn_global_load_lds((const __attribute__((address_space(1))) void*)(gsrc), \
                                     (__attribute__((address_space(3))) void*)(ldst), 16, 0, 0)

// swizzle for 64B rows (4x16B units): rows 2 apart get distinct unit slots;
// uniform 2-way bank aliasing (free per m136) instead of 4-way with (row&3).
#define SWZ4(row) (((row) >> 1) & 3)

// ==================================================================
// prep_a: flag init+detect (block 0), counts zeroing, weight splits.
// ==================================================================
__global__ __launch_bounds__(256)
void prep_a(const void* __restrict__ ei, const float* __restrict__ W1,
            const float* __restrict__ W2, int* __restrict__ flag,
            short* __restrict__ W1h, short* __restrict__ W1l,
            short* __restrict__ W2h, short* __restrict__ W2l,
            int* __restrict__ counts, int N) {
    __shared__ int sflag;
    const int tid = threadIdx.x;
    const int gtid = blockIdx.x * 256 + tid;
    const int gsize = gridDim.x * 256;
    if (blockIdx.x == 0) {
        if (tid == 0) sflag = 0;
        __syncthreads();
        unsigned v = 0;
        for (int i = tid * 2 + 1; i < 2048; i += 512) v |= ((const unsigned*)ei)[i];
        if (v) atomicOr(&sflag, 1);
        __syncthreads();
        if (tid == 0) *flag = sflag;   // nonzero odd words => int32 input
    }
    for (int i = gtid; i < N; i += gsize) counts[i] = 0;
    const int n1 = 256 * 512, n2 = 64 * 256;
    for (int i = gtid; i < n1; i += gsize) {
        float w0 = W1[i];
        unsigned short h = f2bf_u(w0);
        W1h[i] = (short)h;
        W1l[i] = (short)f2bf_u(w0 - bf2f(h));
    }
    for (int i = gtid; i < n2; i += gsize) {
        float w0 = W2[i];
        unsigned short h = f2bf_u(w0);
        W2h[i] = (short)h;
        W2l[i] = (short)f2bf_u(w0 - bf2f(h));
    }
}

__global__ void convert_count_kernel(const void* __restrict__ edges, const int* __restrict__ flag,
                                     int* __restrict__ src, int* __restrict__ dst,
                                     int* __restrict__ counts, int E) {
    int e = blockIdx.x * 256 + threadIdx.x;
    if (e >= E) return;
    int s, d;
    if (*flag) { const int* p = (const int*)edges; s = p[e]; d = p[E + e]; }
    else       { const long long* p = (const long long*)edges; s = (int)p[e]; d = (int)p[E + e]; }
    src[e] = s;
    dst[e] = d;
    atomicAdd(&counts[d], 1);
}

// per-chunk: dinv + block-sum (counts+1: self-loop edge included in CSR)
__global__ void bsum_dinv_kernel(const int* __restrict__ counts, float* __restrict__ dinv,
                                 int* __restrict__ bs, int n) {
    __shared__ int sdata[256];
    int i = blockIdx.x * 256 + threadIdx.x;
    int v = (i < n) ? counts[i] : 0;
    if (i < n) dinv[i] = rsqrtf((float)v + 1.0f);
    sdata[threadIdx.x] = (i < n) ? (v + 1) : 0;
    __syncthreads();
    #pragma unroll
    for (int off = 128; off > 0; off >>= 1) {
        if (threadIdx.x < off) sdata[threadIdx.x] += sdata[threadIdx.x + off];
        __syncthreads();
    }
    if (threadIdx.x == 0) bs[blockIdx.x] = sdata[0];
}

__global__ void scanbs_kernel(const int* __restrict__ bs, int* __restrict__ bsoff, int nb) {
    __shared__ int sdata[256];
    int tid = threadIdx.x;
    int v = (tid < nb) ? bs[tid] : 0;
    sdata[tid] = v;
    __syncthreads();
    #pragma unroll
    for (int off = 1; off < 256; off <<= 1) {
        int t = (tid >= off) ? sdata[tid - off] : 0;
        __syncthreads();
        sdata[tid] += t;
        __syncthreads();
    }
    if (tid < nb) bsoff[tid] = sdata[tid] - v;
}

// scan of (counts+1); writes rowptr, self-loop CSR record, cursor=excl+1
__global__ void scanblock_kernel(const int* __restrict__ counts, const int* __restrict__ bsoff,
                                 const float* __restrict__ dinv,
                                 int* __restrict__ rowptr, int* __restrict__ cursor,
                                 int2* __restrict__ csr, int n) {
    __shared__ int sdata[256];
    int tid = threadIdx.x;
    int i = blockIdx.x * 256 + tid;
    int v = (i < n) ? (counts[i] + 1) : 0;
    sdata[tid] = v;
    __syncthreads();
    #pragma unroll
    for (int off = 1; off < 256; off <<= 1) {
        int t = (tid >= off) ? sdata[tid - off] : 0;
        __syncthreads();
        sdata[tid] += t;
        __syncthreads();
    }
    int excl = bsoff[blockIdx.x] + sdata[tid] - v;
    if (i < n) {
        rowptr[i] = excl;
        float di = dinv[i];
        csr[excl] = make_int2(i, __builtin_bit_cast(int, di * di));  // self edge first
        cursor[i] = excl + 1;
    }
    if (i == n - 1) rowptr[n] = excl + v;
}

__global__ void fill_kernel(const int* __restrict__ src, const int* __restrict__ dst,
                            const float* __restrict__ dinv, int* __restrict__ cursor,
                            int2* __restrict__ csr, int E) {
    int e = blockIdx.x * 256 + threadIdx.x;
    if (e >= E) return;
    int s = src[e], d = dst[e];
    int pos = atomicAdd(&cursor[d], 1);
    float w = dinv[s] * dinv[d];
    csr[pos] = make_int2(s, __builtin_bit_cast(int, w));
}

// ==================================================================
// gemm1f v2 (r14/r17 structure; r20: SWZ4 swizzle kills the 4-way bank
// conflict): BM=256, BN=256, BK=32, 512 thr (8 waves, 2m x 4n),
// 96 KB dynamic LDS, grid = 196 blocks (one round on 256 CUs).
// ==================================================================
__global__ __launch_bounds__(512)
void gemm1f_k(const float* __restrict__ x, const short* __restrict__ Bh,
              const short* __restrict__ Bl, const float* __restrict__ bias,
              short* __restrict__ C, int M) {
    extern __shared__ short lds[];
    short* sA  = lds;              // [2][256*32] shorts (32 KB)
    short* sBh = lds + 16384;      // [2][256*32] (32 KB)
    short* sBl = lds + 32768;      // [2][256*32] (32 KB)
    const int KDIM = 512, LDC = 256;
    const int tid = threadIdx.x, lane = tid & 63, wave = tid >> 6;
    const int wr = wave >> 2, wc = wave & 3;       // 2m x 4n; wave tile 128x64
    const int m0 = blockIdx.x * 256;
    const int lr = lane & 15, lk = lane >> 4;
    const int l4r = lane >> 2, l4u = lane & 3;
    const int arow = tid >> 1, ahalf = tid & 1;

    f32x4 acc[8][4];
    #pragma unroll
    for (int mi = 0; mi < 8; ++mi)
        #pragma unroll
        for (int ni = 0; ni < 4; ++ni) acc[mi][ni] = {0.f, 0.f, 0.f, 0.f};

    float4 fa[4];

    auto a_load = [&](int k0) {
        int grow = m0 + arow; if (grow > M - 1) grow = M - 1;
        const float* s = x + (size_t)grow * KDIM + k0 + ahalf * 16;
        fa[0] = ((const float4*)s)[0];
        fa[1] = ((const float4*)s)[1];
        fa[2] = ((const float4*)s)[2];
        fa[3] = ((const float4*)s)[3];
    };
    auto a_write = [&](int buf) {
        short8 s0, s1;
        s0[0] = (short)f2bf_u(fa[0].x); s0[1] = (short)f2bf_u(fa[0].y);
        s0[2] = (short)f2bf_u(fa[0].z); s0[3] = (short)f2bf_u(fa[0].w);
        s0[4] = (short)f2bf_u(fa[1].x); s0[5] = (short)f2bf_u(fa[1].y);
        s0[6] = (short)f2bf_u(fa[1].z); s0[7] = (short)f2bf_u(fa[1].w);
        s1[0] = (short)f2bf_u(fa[2].x); s1[1] = (short)f2bf_u(fa[2].y);
        s1[2] = (short)f2bf_u(fa[2].z); s1[3] = (short)f2bf_u(fa[2].w);
        s1[4] = (short)f2bf_u(fa[3].x); s1[5] = (short)f2bf_u(fa[3].y);
        s1[6] = (short)f2bf_u(fa[3].z); s1[7] = (short)f2bf_u(fa[3].w);
        int b = buf * 8192 + arow * 32;
        int c = SWZ4(arow);
        *reinterpret_cast<short8*>(&sA[b + (((2 * ahalf)     ^ c) << 3)]) = s0;
        *reinterpret_cast<short8*>(&sA[b + (((2 * ahalf + 1) ^ c) << 3)]) = s1;
    };
    auto b_dma = [&](int buf, int k0) {
        #pragma unroll
        for (int p = 0; p < 2; ++p) {
            int row = p * 128 + wave * 16 + l4r;
            size_t goff = (size_t)row * KDIM + k0 + ((l4u ^ SWZ4(row)) << 3);
            int db = buf * 8192 + (p * 128 + wave * 16) * 32;
            GLOAD_LDS16(Bh + goff, sBh + db);
            GLOAD_LDS16(Bl + goff, sBl + db);
        }
    };

    a_load(0);
    b_dma(0, 0);
    asm volatile("s_waitcnt vmcnt(0)" ::: "memory");
    a_write(0);
    __syncthreads();

    int cur = 0;
    #pragma unroll 1
    for (int t = 0; t < 16; ++t) {
        const bool pf = (t < 15);
        if (pf) {
            a_load((t + 1) * 32);
            b_dma(cur ^ 1, (t + 1) * 32);
        }
        {
            bf16x8 af[8], bhf[4], blf[4];
            #pragma unroll
            for (int mi = 0; mi < 8; ++mi) {
                int row = wr * 128 + mi * 16 + lr;
                af[mi] = *reinterpret_cast<const bf16x8*>(
                    &sA[cur * 8192 + row * 32 + ((lk ^ SWZ4(row)) << 3)]);
            }
            #pragma unroll
            for (int ni = 0; ni < 4; ++ni) {
                int row = wc * 64 + ni * 16 + lr;
                int idx = cur * 8192 + row * 32 + ((lk ^ SWZ4(row)) << 3);
                bhf[ni] = *reinterpret_cast<const bf16x8*>(&sBh[idx]);
                blf[ni] = *reinterpret_cast<const bf16x8*>(&sBl[idx]);
            }
            #pragma unroll
            for (int mi = 0; mi < 8; ++mi)
                #pragma unroll
                for (int ni = 0; ni < 4; ++ni) {
                    acc[mi][ni] = __builtin_amdgcn_mfma_f32_16x16x32_bf16(af[mi], bhf[ni], acc[mi][ni], 0, 0, 0);
                    acc[mi][ni] = __builtin_amdgcn_mfma_f32_16x16x32_bf16(af[mi], blf[ni], acc[mi][ni], 0, 0, 0);
                }
        }
        asm volatile("s_waitcnt vmcnt(0)" ::: "memory");
        if (pf) a_write(cur ^ 1);
        __syncthreads();
        cur ^= 1;
    }

    #pragma unroll
    for (int ni = 0; ni < 4; ++ni) {
        int col = wc * 64 + ni * 16 + lr;
        float bv = bias[col];
        #pragma unroll
        for (int mi = 0; mi < 8; ++mi) {
            #pragma unroll
            for (int r = 0; r < 4; ++r) {
                int row = m0 + wr * 128 + mi * 16 + lk * 4 + r;
                if (row < M) {
                    float v = fmaxf(acc[mi][ni][r] + bv, 0.0f);
                    C[(size_t)row * LDC + col] = (short)f2bf_u(v);
                }
            }
        }
    }
}

// ==================================================================
// Fallback / gemm2 tile (r10-proven). BM=128, BN=64, BK=64, 8 waves 4x2.
// ==================================================================
template<int KDIM, int LDC, bool AF32, bool RELU>
__device__ __forceinline__
void gemm_tile(const void* __restrict__ Av, const short* __restrict__ Bh,
               const short* __restrict__ Bl, const float* __restrict__ bias,
               short* __restrict__ C, int M, int m0, int n0,
               short* sAp, short* sBp) {
    constexpr int NT = KDIM / 64;
    const int tid  = threadIdx.x;
    const int lane = tid & 63;
    const int wave = tid >> 6;
    const int wr = wave >> 1, wc = wave & 1;
    const int lr = lane & 15;
    const int lk = lane >> 4;
    const int l8r = lane >> 3;
    const int l8u = lane & 7;
    const int tr = tid >> 3;
    const int tk = tid & 7;

    f32x4 acc[2][2];
    #pragma unroll
    for (int mi = 0; mi < 2; ++mi)
        #pragma unroll
        for (int ni = 0; ni < 2; ++ni) acc[mi][ni] = {0.f, 0.f, 0.f, 0.f};

    float4 fa[2][2];

    auto a_load = [&](int k0) {
        #pragma unroll
        for (int p = 0; p < 2; ++p) {
            int row = p * 64 + tr;
            int grow = m0 + row; if (grow > M - 1) grow = M - 1;
            const float* s = (const float*)Av + (size_t)grow * KDIM + k0 + tk * 8;
            fa[p][0] = *reinterpret_cast<const float4*>(s);
            fa[p][1] = *reinterpret_cast<const float4*>(s + 4);
        }
    };
    auto a_write = [&](int buf) {
        #pragma unroll
        for (int p = 0; p < 2; ++p) {
            int row = p * 64 + tr;
            short8 sh;
            sh[0] = (short)f2bf_u(fa[p][0].x); sh[1] = (short)f2bf_u(fa[p][0].y);
            sh[2] = (short)f2bf_u(fa[p][0].z); sh[3] = (short)f2bf_u(fa[p][0].w);
            sh[4] = (short)f2bf_u(fa[p][1].x); sh[5] = (short)f2bf_u(fa[p][1].y);
            sh[6] = (short)f2bf_u(fa[p][1].z); sh[7] = (short)f2bf_u(fa[p][1].w);
            *reinterpret_cast<short8*>(&sAp[buf * 8192 + row * 64 + ((tk ^ (row & 7)) << 3)]) = sh;
        }
    };
    auto a_dma = [&](int buf, int k0) {
        #pragma unroll
        for (int p = 0; p < 2; ++p) {
            int row = p * 64 + wave * 8 + l8r;
            int grow = m0 + row; if (grow > M - 1) grow = M - 1;
            const short* s = (const short*)Av + (size_t)grow * KDIM + k0 + ((l8u ^ (row & 7)) << 3);
            GLOAD_LDS16(s, sAp + buf * 8192 + p * 4096 + wave * 512);
        }
    };
    auto b_dma = [&](int buf, int k0) {
        int row = wave * 8 + l8r;
        size_t goff = (size_t)(n0 + row) * KDIM + k0 + ((l8u ^ (row & 7)) << 3);
        GLOAD_LDS16(Bh + goff, sBp + (buf * 2 + 0) * 4096 + wave * 512);
        GLOAD_LDS16(Bl + goff, sBp + (buf * 2 + 1) * 4096 + wave * 512);
    };

    if (AF32) {
        a_load(0);
        b_dma(0, 0);
        asm volatile("s_waitcnt vmcnt(0)" ::: "memory");
        a_write(0);
        __syncthreads();
    } else {
        a_dma(0, 0);
        b_dma(0, 0);
        asm volatile("s_waitcnt vmcnt(0)" ::: "memory");
        __builtin_amdgcn_s_barrier();
        asm volatile("" ::: "memory");
    }

    int cur = 0;
    #pragma unroll 1
    for (int t = 0; t < NT; ++t) {
        const bool pf = (t + 1 < NT);
        if (pf) {
            if (AF32) a_load((t + 1) * 64);
            else      a_dma(cur ^ 1, (t + 1) * 64);
            b_dma(cur ^ 1, (t + 1) * 64);
        }
        #pragma unroll
        for (int ks = 0; ks < 2; ++ks) {
            int kg = ks * 4 + lk;
            bf16x8 af[2], bhf[2], blf[2];
            #pragma unroll
            for (int mi = 0; mi < 2; ++mi) {
                int row = wr * 32 + mi * 16 + lr;
                af[mi] = *reinterpret_cast<const bf16x8*>(
                    &sAp[cur * 8192 + row * 64 + ((kg ^ (row & 7)) << 3)]);
            }
            #pragma unroll
            for (int ni = 0; ni < 2; ++ni) {
                int row = wc * 32 + ni * 16 + lr;
                int idx = row * 64 + ((kg ^ (row & 7)) << 3);
                bhf[ni] = *reinterpret_cast<const bf16x8*>(&sBp[(cur * 2 + 0) * 4096 + idx]);
                blf[ni] = *reinterpret_cast<const bf16x8*>(&sBp[(cur * 2 + 1) * 4096 + idx]);
            }
            #pragma unroll
            for (int mi = 0; mi < 2; ++mi)
                #pragma unroll
                for (int ni = 0; ni < 2; ++ni) {
                    acc[mi][ni] = __builtin_amdgcn_mfma_f32_16x16x32_bf16(af[mi], bhf[ni], acc[mi][ni], 0, 0, 0);
                    acc[mi][ni] = __builtin_amdgcn_mfma_f32_16x16x32_bf16(af[mi], blf[ni], acc[mi][ni], 0, 0, 0);
                }
        }
        asm volatile("s_waitcnt vmcnt(0)" ::: "memory");
        if (AF32) { if (pf) a_write(cur ^ 1); __syncthreads(); }
        else { __builtin_amdgcn_s_barrier(); asm volatile("" ::: "memory"); }
        cur ^= 1;
    }

    #pragma unroll
    for (int ni = 0; ni < 2; ++ni) {
        int col = n0 + wc * 32 + ni * 16 + lr;
        float bv = bias[col];
        #pragma unroll
        for (int mi = 0; mi < 2; ++mi) {
            #pragma unroll
            for (int r = 0; r < 4; ++r) {
                int row = m0 + wr * 32 + mi * 16 + lk * 4 + r;
                if (row < M) {
                    float v = acc[mi][ni][r] + bv;
                    if (RELU) v = fmaxf(v, 0.0f);
                    C[(size_t)row * LDC + col] = (short)f2bf_u(v);
                }
            }
        }
    }
}

__global__ __launch_bounds__(512)
void gemm1_k(const float* __restrict__ x, const short* __restrict__ W1h,
             const short* __restrict__ W1l, const float* __restrict__ b1,
             short* __restrict__ Hbf, int M) {
    __shared__ short sAp[2 * 128 * 64];
    __shared__ short sBp[2 * 2 * 64 * 64];
    int t = blockIdx.x;
    gemm_tile<512, 256, true, true>(x, W1h, W1l, b1, Hbf, M, (t >> 2) * 128, (t & 3) * 64, sAp, sBp);
}

__global__ __launch_bounds__(512)
void gemm2_k(const short* __restrict__ Hbf, const short* __restrict__ W2h,
             const short* __restrict__ W2l, const float* __restrict__ b2,
             short* __restrict__ zbf, int M) {
    __shared__ short sAp[2 * 128 * 64];
    __shared__ short sBp[2 * 2 * 64 * 64];
    gemm_tile<256, 64, false, false>(Hbf, W2h, W2l, b2, zbf, M, blockIdx.x * 128, 0, sAp, sBp);
}

// ==================================================================
// Propagation v5 (r17-proven): grid-stride 2048 blocks; one wave/node;
// scalar csr via readfirstlane; 8-deep gather; self-edge CSR.
// ==================================================================
__global__ __launch_bounds__(256)
void prop_step(const unsigned short* __restrict__ hin, const unsigned short* __restrict__ zbf,
               const int* __restrict__ rowptr, const int2* __restrict__ csr,
               void* __restrict__ hout, int outf32, int n) {
    const int lane = threadIdx.x & 63;
    const int nwaves = gridDim.x * 4;
    for (int node = blockIdx.x * 4 + (threadIdx.x >> 6); node < n; node += nwaves) {
        int base = node << 6;
        float acc = 0.0f;
        int e  = __builtin_amdgcn_readfirstlane(rowptr[node]);
        int e1 = __builtin_amdgcn_readfirstlane(rowptr[node + 1]);

        for (; e + 8 <= e1; e += 8) {
            int2 r[8]; unsigned short v[8];
            #pragma unroll
            for (int j = 0; j < 8; ++j) r[j] = csr[e + j];
            #pragma unroll
            for (int j = 0; j < 8; ++j) v[j] = hin[((unsigned)r[j].x << 6) + lane];
            #pragma unroll
            for (int j = 0; j < 8; ++j) acc = fmaf(bf2f(v[j]), i2f(r[j].y), acc);
        }
        for (; e + 4 <= e1; e += 4) {
            int2 r[4]; unsigned short v[4];
            #pragma unroll
            for (int j = 0; j < 4; ++j) r[j] = csr[e + j];
            #pragma unroll
            for (int j = 0; j < 4; ++j) v[j] = hin[((unsigned)r[j].x << 6) + lane];
            #pragma unroll
            for (int j = 0; j < 4; ++j) acc = fmaf(bf2f(v[j]), i2f(r[j].y), acc);
        }
        for (; e < e1; ++e) {
            int2 r = csr[e];
            acc = fmaf(bf2f(hin[((unsigned)r.x << 6) + lane]), i2f(r.y), acc);
        }

        float res = 0.9f * acc + 0.1f * bf2f(zbf[base + lane]);
        if (outf32) ((float*)hout)[base + lane] = res;
        else        ((unsigned short*)hout)[base + lane] = f2bf_u(res);
    }
}

// ==================================================================
extern "C" void kernel_launch(void* const* d_in, const int* in_sizes, int n_in,
                              void* d_out, int out_size, void* d_ws, size_t ws_size,
                              hipStream_t stream) {
    const float* x  = (const float*)d_in[0];
    const void*  ei = d_in[1];
    const float* W1 = (const float*)d_in[2];
    const float* b1 = (const float*)d_in[3];
    const float* W2 = (const float*)d_in[4];
    const float* b2 = (const float*)d_in[5];
    float* dout = (float*)d_out;

    const int IN_C = 512, HID_C = 256, OUT_C = 64, Ksteps = 10;
    const int N = in_sizes[0] / IN_C;   // 50000
    const int E = in_sizes[1] / 2;      // 800000

    char* w = (char*)d_ws;
    auto alloc = [&](size_t bytes) { char* p = w; w += (bytes + 255) & ~(size_t)255; return p; };
    int*   flag    = (int*)  alloc(4);
    int*   src32   = (int*)  alloc((size_t)E * 4);
    int*   dst32   = (int*)  alloc((size_t)E * 4);
    int*   counts  = (int*)  alloc((size_t)N * 4);
    int*   rowptr  = (int*)  alloc((size_t)(N + 1) * 4);
    int*   cursor  = (int*)  alloc((size_t)N * 4);
    float* dinv    = (float*)alloc((size_t)N * 4);
    int2*  csr     = (int2*) alloc((size_t)(E + N) * 8);   // +N self edges
    short* W1h     = (short*)alloc((size_t)HID_C * IN_C * 2);
    short* W1l     = (short*)alloc((size_t)HID_C * IN_C * 2);
    short* W2h     = (short*)alloc((size_t)OUT_C * HID_C * 2);
    short* W2l     = (short*)alloc((size_t)OUT_C * HID_C * 2);
    short* Hbf     = (short*)alloc((size_t)N * HID_C * 2);
    unsigned short* zbf = (unsigned short*)alloc((size_t)N * OUT_C * 2);
    unsigned short* hA  = (unsigned short*)alloc((size_t)N * OUT_C * 2);
    unsigned short* hB  = (unsigned short*)alloc((size_t)N * OUT_C * 2);
    int*   bs      = (int*)  alloc(256 * 4);
    int*   bsoff   = (int*)  alloc(256 * 4);

    const int egrid = (E + 255) / 256;
    const int nblk = (N + 255) / 256;

    // preprocessing (6 dispatches, no memsets)
    prep_a<<<512, 256, 0, stream>>>(ei, W1, W2, flag, W1h, W1l, W2h, W2l, counts, N);
    convert_count_kernel<<<egrid, 256, 0, stream>>>(ei, flag, src32, dst32, counts, E);
    bsum_dinv_kernel<<<nblk, 256, 0, stream>>>(counts, dinv, bs, N);
    scanbs_kernel<<<1, 256, 0, stream>>>(bs, bsoff, nblk);
    scanblock_kernel<<<nblk, 256, 0, stream>>>(counts, bsoff, dinv, rowptr, cursor, csr, N);
    fill_kernel<<<egrid, 256, 0, stream>>>(src32, dst32, dinv, cursor, csr, E);

    // GEMM1: BM=256/BN=256/BK=32, 96 KB dynamic LDS; fallback r10
    constexpr int G1_LDS = 98304;
    const int g1grid = (N + 255) / 256;
    bool big = hipFuncSetAttribute((const void*)gemm1f_k,
                                   hipFuncAttributeMaxDynamicSharedMemorySize,
                                   G1_LDS) == hipSuccess;
    if (big) {
        gemm1f_k<<<g1grid, 512, G1_LDS, stream>>>(x, W1h, W1l, b1, Hbf, N);
        if (hipGetLastError() != hipSuccess) big = false;
    }
    if (!big) {
        gemm1_k<<<((N + 127) / 128) * 4, 512, 0, stream>>>(x, W1h, W1l, b1, Hbf, N);
    }
    gemm2_k<<<(N + 127) / 128, 512, 0, stream>>>(Hbf, W2h, W2l, b2, (short*)zbf, N);

    // propagation: grid-stride 2048 blocks; h^(0)=z in zbf; ping-pong hA/hB;
    // last step writes fp32 dout
    const unsigned short* pin = zbf;
    for (int s = 0; s < Ksteps; ++s) {
        bool last = (s == Ksteps - 1);
        void* out = last ? (void*)dout : ((s & 1) ? (void*)hB : (void*)hA);
        prop_step<<<2048, 256, 0, stream>>>(pin, zbf, rowptr, csr,
                                            out, last ? 1 : 0, N);
        pin = (const unsigned short*)out;
    }
}